// Round 1
// baseline (152.728 us; speedup 1.0000x reference)
//
#include <hip/hip_runtime.h>
#include <hip/hip_cooperative_groups.h>
#include <math.h>

namespace cg = cooperative_groups;

// Problem constants
#define BB 16      // batch
#define LL 32      // L
#define AA 2046    // attributor cols
#define MM 2048    // M = A + 2
#define NROWS 192  // 6L

#define NBLK 256   // 16 b x 16 column-tiles  (== #CUs, 1 block/CU co-resident)
#define NTHR 512   // 8 waves/block

// Workspace layout (floats):  c[2][16][2048]  causal weights for cols {0, M-1}

// ---------------------------------------------------------------------------
// Single fused cooperative kernel.
// Phase A (per block = (b, ctile)):
//   1. redundant prep: K/Q boundary projections -> u_j[r], v_j[r] weights
//   2. s/t partials for 128 columns (4 r-quarters across tid>>7), fused
//      cweight -> c_j[b,n] written with agent-scope stores
//   3. block 0 zeroes the output
// grid.sync()
// Phase B (per block = (b, rvtile)):
//   stage c to LDS, gather g_j[r] = sum_n relu(raw)*c_j[n] for 4 value rows,
//   wave-shuffle reduce, out += W2^T g via one atomicAdd per (l,j).
// ---------------------------------------------------------------------------
__global__ __launch_bounds__(NTHR) void fused_kernel(
    const float* __restrict__ user, const float* __restrict__ item,
    const float* __restrict__ att, const float* __restrict__ adj,
    const float* __restrict__ iw, const float* __restrict__ W1,
    const float* __restrict__ W2, float* __restrict__ c,
    float* __restrict__ out) {
  cg::grid_group grid = cg::this_grid();
  const int bid = blockIdx.x, tid = threadIdx.x;
  const int b = bid >> 4, ctile = bid & 15;

  __shared__ float KQ[4][LL];
  __shared__ float uvs[4][64];
  __shared__ float stS[4][128][2];
  __shared__ float cs0[MM], cs1[MM];
  __shared__ float wred[8][4][2];

  // ---- Phase A.1: prep (redundant per block, trivial cost) ----
  if (tid < 128) {
    const int q = tid >> 5, l = tid & 31;
    const float* __restrict__ src = (q == 0 || q == 2) ? user : item;
    const int rbase = (q < 2) ? 64 : 0;  // K rows 64..127, Q rows 0..63
    float acc = 0.f;
#pragma unroll
    for (int r = 0; r < 64; ++r)
      acc += fmaxf(src[b * NROWS + rbase + r], 0.f) * W2[(rbase + r) * LL + l];
    KQ[q][l] = acc;  // 0:K0(user) 1:K1(item) 2:Q0(user) 3:Q1(item)
  }
  __syncthreads();
  if (tid < 256) {
    const int which = tid >> 6, r = tid & 63;
    const int wrow = (which < 2) ? r : 64 + r;
    float acc = 0.f;
#pragma unroll
    for (int l = 0; l < LL; ++l) acc += W2[wrow * LL + l] * KQ[which][l];
    uvs[which][r] = acc;  // 0:u0 1:u1 2:v0 3:v1
  }
  __syncthreads();

  // ---- Phase A.2: s/t partials over 32-row quarters ----
  {
    const int colidx = tid & 127, q = tid >> 7;  // q: 0,1 -> s (u); 2,3 -> t (v)
    const int col = ctile * 128 + colidx;
    const int r0 = q * 32;
    const float* __restrict__ wj0 = uvs[(q < 2) ? 0 : 2];
    const float* __restrict__ wj1 = uvs[(q < 2) ? 1 : 3];
    const int wbase = (q < 2) ? 0 : 64;
    float a0 = 0.f, a1 = 0.f;
    if (col < AA) {  // interior column n = col+1
#pragma unroll
      for (int i = 0; i < 32; ++i) {
        const int r = r0 + i;
        const float v = fmaxf(
            att[((size_t)(b * NROWS + r)) * AA + col] * W1[(size_t)r * AA + col],
            0.f);
        a0 += v * wj0[r - wbase];
        a1 += v * wj1[r - wbase];
      }
    } else {  // col==2046 -> n=0 (user col), col==2047 -> n=M-1 (item col)
      const float* __restrict__ src = (col == AA) ? user : item;
#pragma unroll
      for (int i = 0; i < 32; ++i) {
        const int r = r0 + i;
        const float v = fmaxf(src[b * NROWS + r], 0.f);
        a0 += v * wj0[r - wbase];
        a1 += v * wj1[r - wbase];
      }
    }
    stS[q][colidx][0] = a0;
    stS[q][colidx][1] = a1;
  }
  __syncthreads();

  // ---- fused cweight for this block's 128 columns ----
  if (tid < 128) {
    const int i = tid;
    const int cc = ctile * 128 + i;
    const int n = (cc < AA) ? cc + 1 : ((cc == AA) ? 0 : MM - 1);
    const float s0 = stS[0][i][0] + stS[1][i][0];
    const float s1 = stS[0][i][1] + stS[1][i][1];
    const float t0 = stS[2][i][0] + stS[3][i][0];
    const float t1 = stS[2][i][1] + stS[3][i][1];
    const float an0 = adj[(size_t)n * MM];
    const float an1 = adj[(size_t)n * MM + (MM - 1)];
    const float wn0 = an0 * iw[(size_t)n * MM];
    const float wn1 = an1 * iw[(size_t)n * MM + (MM - 1)];
    const float w0n = adj[n] * iw[n];
    const float w1n =
        adj[(size_t)(MM - 1) * MM + n] * iw[(size_t)(MM - 1) * MM + n];
    const float d0 = s0 * wn0 - t0 * w0n;
    const float d1 = s1 * wn1 - t1 * w1n;
    const float e0 = expf(-fabsf(d0));
    const float e1 = expf(-fabsf(d1));
    const float sig0 = (d0 > 0.f) ? 1.f / (1.f + e0) : e0 / (1.f + e0);
    const float sig1 = (d1 > 0.f) ? 1.f / (1.f + e1) : e1 / (1.f + e1);
    __hip_atomic_store(&c[b * MM + n], sig0 * an0, __ATOMIC_RELAXED,
                       __HIP_MEMORY_SCOPE_AGENT);
    __hip_atomic_store(&c[BB * MM + b * MM + n], sig1 * an1, __ATOMIC_RELAXED,
                       __HIP_MEMORY_SCOPE_AGENT);
  }

  // ---- block 0 zeroes the 1024-float output (visible after grid.sync) ----
  if (bid == 0) {
    __hip_atomic_store(&out[tid], 0.f, __ATOMIC_RELAXED,
                       __HIP_MEMORY_SCOPE_AGENT);
    __hip_atomic_store(&out[tid + NTHR], 0.f, __ATOMIC_RELAXED,
                       __HIP_MEMORY_SCOPE_AGENT);
  }

  grid.sync();

  // ---- Phase B: gather. block = (b, rvtile of 4 value-rows) ----
  const int gb = bid >> 4, rvt = bid & 15;
#pragma unroll
  for (int k = 0; k < 4; ++k) {
    const int idx = k * NTHR + tid;
    cs0[idx] = __hip_atomic_load(&c[gb * MM + idx], __ATOMIC_RELAXED,
                                 __HIP_MEMORY_SCOPE_AGENT);
    cs1[idx] = __hip_atomic_load(&c[BB * MM + gb * MM + idx], __ATOMIC_RELAXED,
                                 __HIP_MEMORY_SCOPE_AGENT);
  }
  __syncthreads();

#pragma unroll
  for (int k = 0; k < 4; ++k) {
    const int r = 128 + rvt * 4 + k;
    float g0 = 0.f, g1 = 0.f;
#pragma unroll
    for (int ch = 0; ch < 4; ++ch) {
      const int cl = ch * NTHR + tid;
      if (cl < AA) {
        const float v = fmaxf(att[((size_t)(gb * NROWS + r)) * AA + cl] *
                                  W1[(size_t)r * AA + cl],
                              0.f);
        g0 += v * cs0[cl + 1];
        g1 += v * cs1[cl + 1];
      }
    }
    if (tid == NTHR - 2) {  // boundary m=0: user column
      const float v = fmaxf(user[gb * NROWS + r], 0.f);
      g0 += v * cs0[0];
      g1 += v * cs1[0];
    }
    if (tid == NTHR - 1) {  // boundary m=M-1: item column
      const float v = fmaxf(item[gb * NROWS + r], 0.f);
      g0 += v * cs0[MM - 1];
      g1 += v * cs1[MM - 1];
    }
#pragma unroll
    for (int s = 32; s >= 1; s >>= 1) {
      g0 += __shfl_xor(g0, s, 64);
      g1 += __shfl_xor(g1, s, 64);
    }
    if ((tid & 63) == 0) {
      wred[tid >> 6][k][0] = g0;
      wred[tid >> 6][k][1] = g1;
    }
  }
  __syncthreads();
  if (tid < 64) {
    const int l = tid & 31, j = tid >> 5;
    float acc = 0.f;
#pragma unroll
    for (int k = 0; k < 4; ++k) {
      float gk = 0.f;
#pragma unroll
      for (int w = 0; w < 8; ++w) gk += wred[w][k][j];
      acc += W2[(128 + rvt * 4 + k) * LL + l] * gk;
    }
    atomicAdd(&out[gb * (LL * 2) + l * 2 + j], acc);
  }
}

extern "C" void kernel_launch(void* const* d_in, const int* in_sizes, int n_in,
                              void* d_out, int out_size, void* d_ws,
                              size_t ws_size, hipStream_t stream) {
  const float* user = (const float*)d_in[0];
  const float* item = (const float*)d_in[1];
  const float* att = (const float*)d_in[2];
  const float* adj = (const float*)d_in[3];
  const float* iw = (const float*)d_in[4];
  const float* W1 = (const float*)d_in[5];
  const float* W2 = (const float*)d_in[6];
  float* out = (float*)d_out;
  float* c = (float*)d_ws;  // 2*16*2048 floats

  void* args[] = {(void*)&user, (void*)&item, (void*)&att,
                  (void*)&adj,  (void*)&iw,   (void*)&W1,
                  (void*)&W2,   (void*)&c,    (void*)&out};
  hipLaunchCooperativeKernel((const void*)fused_kernel, dim3(NBLK), dim3(NTHR),
                             args, 0, stream);
}

// Round 2
// 113.856 us; speedup vs baseline: 1.3414x; 1.3414x over previous
//
#include <hip/hip_runtime.h>
#include <math.h>

// Problem constants
#define BB 16      // batch
#define LL 32      // L
#define AA 2046    // attributor cols
#define MM 2048    // M = A + 2
#define NROWS 192  // 6L

// Workspace layout (floats): c[2][16][2048] causal weights for cols {0, M-1}

// ---------------------------------------------------------------------------
// Kernel A: prep + s/t partials + causal weights, fused.
// grid (16 ctiles, 16 b) x 256 threads. Each block owns 128 columns.
//   prep: redundant per block (tiny): K/Q projections -> u_j/v_j weights.
//   st:   thread (g = tid&63, q = tid>>6) accumulates 2 cols (float2) over
//         32 rows (quarter q). q<2 -> s (rows 0..63, u); q>=2 -> t (rows
//         64..127, v). Boundary cols 2046/2047 map to user(n=0)/item(n=M-1).
//   cweight: 128 threads combine quarters -> c_j[b,n] = sigmoid(d_j)*adj.
//   block (0,0) also zeroes out[] (visible to kernel B via stream order).
// ---------------------------------------------------------------------------
__global__ __launch_bounds__(256) void stc_kernel(
    const float* __restrict__ user, const float* __restrict__ item,
    const float* __restrict__ att, const float* __restrict__ adj,
    const float* __restrict__ iw, const float* __restrict__ W1,
    const float* __restrict__ W2, float* __restrict__ c,
    float* __restrict__ out) {
  const int ctile = blockIdx.x, b = blockIdx.y, tid = threadIdx.x;
  __shared__ float KQ[4][LL];
  __shared__ float uvs[4][64];
  __shared__ float stS[4][64][2][2];  // [quarter][colgroup][colpair][j]

  if (ctile == 0 && b == 0) {  // zero the 1024-float output
    out[tid] = 0.f;
    out[tid + 256] = 0.f;
    out[tid + 512] = 0.f;
    out[tid + 768] = 0.f;
  }

  // ---- prep stage 1: K/Q boundary projections ----
  if (tid < 128) {
    const int q = tid >> 5, l = tid & 31;
    const float* __restrict__ src = (q == 0 || q == 2) ? user : item;
    const int rbase = (q < 2) ? 64 : 0;  // K rows 64..127, Q rows 0..63
    float acc = 0.f;
#pragma unroll
    for (int r = 0; r < 64; ++r)
      acc += fmaxf(src[b * NROWS + rbase + r], 0.f) * W2[(rbase + r) * LL + l];
    KQ[q][l] = acc;  // 0:K0(user) 1:K1(item) 2:Q0(user) 3:Q1(item)
  }
  __syncthreads();
  {
    const int which = tid >> 6, r = tid & 63;
    const int wrow = (which < 2) ? r : 64 + r;
    float acc = 0.f;
#pragma unroll
    for (int l = 0; l < LL; ++l) acc += W2[wrow * LL + l] * KQ[which][l];
    uvs[which][r] = acc;  // 0:u0 1:u1 2:v0 3:v1
  }
  __syncthreads();

  // ---- s/t partials: 2 cols/thread (float2), 32 rows/quarter ----
  {
    const int g = tid & 63, q = tid >> 6;
    const int col0 = ctile * 128 + g * 2;
    const int r0 = q * 32;
    const float* __restrict__ wj0 = uvs[(q < 2) ? 0 : 2];
    const float* __restrict__ wj1 = uvs[(q < 2) ? 1 : 3];
    const int wbase = (q < 2) ? 0 : 64;
    float a00 = 0.f, a01 = 0.f, a10 = 0.f, a11 = 0.f;  // [col][j]
    if (col0 < AA) {  // interior: n = col+1 (row base even + even col -> 8B ok)
#pragma unroll 8
      for (int i = 0; i < 32; ++i) {
        const int r = r0 + i;
        const float2 av =
            *(const float2*)(att + ((size_t)(b * NROWS + r)) * AA + col0);
        const float2 wv = *(const float2*)(W1 + (size_t)r * AA + col0);
        const float v0 = fmaxf(av.x * wv.x, 0.f);
        const float v1 = fmaxf(av.y * wv.y, 0.f);
        const float u0 = wj0[r - wbase], u1 = wj1[r - wbase];
        a00 += v0 * u0;
        a01 += v0 * u1;
        a10 += v1 * u0;
        a11 += v1 * u1;
      }
    } else {  // col0==2046: col 2046 -> user (n=0), col 2047 -> item (n=M-1)
#pragma unroll
      for (int i = 0; i < 32; ++i) {
        const int r = r0 + i;
        const float vu = fmaxf(user[b * NROWS + r], 0.f);
        const float vi = fmaxf(item[b * NROWS + r], 0.f);
        const float u0 = wj0[r - wbase], u1 = wj1[r - wbase];
        a00 += vu * u0;
        a01 += vu * u1;
        a10 += vi * u0;
        a11 += vi * u1;
      }
    }
    *(float4*)&stS[q][g][0][0] = make_float4(a00, a01, a10, a11);
  }
  __syncthreads();

  // ---- cweight for this block's 128 columns ----
  if (tid < 128) {
    const int g = tid >> 1, cp = tid & 1;
    const int col = ctile * 128 + tid;
    const int n = (col < AA) ? col + 1 : ((col == AA) ? 0 : MM - 1);
    const float s0 = stS[0][g][cp][0] + stS[1][g][cp][0];
    const float s1 = stS[0][g][cp][1] + stS[1][g][cp][1];
    const float t0 = stS[2][g][cp][0] + stS[3][g][cp][0];
    const float t1 = stS[2][g][cp][1] + stS[3][g][cp][1];
    const float an0 = adj[(size_t)n * MM];
    const float an1 = adj[(size_t)n * MM + (MM - 1)];
    const float wn0 = an0 * iw[(size_t)n * MM];
    const float wn1 = an1 * iw[(size_t)n * MM + (MM - 1)];
    const float w0n = adj[n] * iw[n];
    const float w1n =
        adj[(size_t)(MM - 1) * MM + n] * iw[(size_t)(MM - 1) * MM + n];
    const float d0 = s0 * wn0 - t0 * w0n;
    const float d1 = s1 * wn1 - t1 * w1n;
    const float e0 = expf(-fabsf(d0));
    const float e1 = expf(-fabsf(d1));
    const float sig0 = (d0 > 0.f) ? 1.f / (1.f + e0) : e0 / (1.f + e0);
    const float sig1 = (d1 > 0.f) ? 1.f / (1.f + e1) : e1 / (1.f + e1);
    c[b * MM + n] = sig0 * an0;
    c[BB * MM + b * MM + n] = sig1 * an1;
  }
}

// ---------------------------------------------------------------------------
// Kernel B: gather + output projection.
// grid (16 rvt, 16 b) x 256 threads. Each block owns 4 value rows.
//   stage c (float4) -> LDS; per row accumulate sum_n relu(att*W1)*c[n]
//   via float2 loads; wave-shuffle reduce; out += W2^T g (one atomicAdd
//   per (l,j) per block).
// ---------------------------------------------------------------------------
__global__ __launch_bounds__(256) void gather_kernel(
    const float* __restrict__ user, const float* __restrict__ item,
    const float* __restrict__ att, const float* __restrict__ W1,
    const float* __restrict__ c, const float* __restrict__ W2,
    float* __restrict__ out) {
  const int rvt = blockIdx.x, gb = blockIdx.y, tid = threadIdx.x;
  __shared__ float cs0[MM], cs1[MM];
  __shared__ float wred[4][4][2];

  {  // stage c to LDS, float4
    const float4* __restrict__ c0p = (const float4*)(c + gb * MM);
    const float4* __restrict__ c1p = (const float4*)(c + BB * MM + gb * MM);
    float4* s0p = (float4*)cs0;
    float4* s1p = (float4*)cs1;
#pragma unroll
    for (int i = 0; i < 2; ++i) {
      s0p[i * 256 + tid] = c0p[i * 256 + tid];
      s1p[i * 256 + tid] = c1p[i * 256 + tid];
    }
  }
  __syncthreads();

#pragma unroll
  for (int k = 0; k < 4; ++k) {
    const int r = 128 + rvt * 4 + k;
    const size_t arow = (size_t)(gb * NROWS + r) * AA;
    const size_t wrow = (size_t)r * AA;
    float g0 = 0.f, g1 = 0.f;
#pragma unroll
    for (int ch = 0; ch < 4; ++ch) {
      const int cl = (ch * 256 + tid) * 2;
      if (cl < AA) {
        const float2 av = *(const float2*)(att + arow + cl);
        const float2 wv = *(const float2*)(W1 + wrow + cl);
        const float v0 = fmaxf(av.x * wv.x, 0.f);
        const float v1 = fmaxf(av.y * wv.y, 0.f);
        g0 += v0 * cs0[cl + 1] + v1 * cs0[cl + 2];
        g1 += v0 * cs1[cl + 1] + v1 * cs1[cl + 2];
      }
    }
    if (tid == 0) {  // boundary m=0: user column
      const float v = fmaxf(user[gb * NROWS + r], 0.f);
      g0 += v * cs0[0];
      g1 += v * cs1[0];
    }
    if (tid == 1) {  // boundary m=M-1: item column
      const float v = fmaxf(item[gb * NROWS + r], 0.f);
      g0 += v * cs0[MM - 1];
      g1 += v * cs1[MM - 1];
    }
#pragma unroll
    for (int s = 32; s >= 1; s >>= 1) {
      g0 += __shfl_xor(g0, s, 64);
      g1 += __shfl_xor(g1, s, 64);
    }
    if ((tid & 63) == 0) {
      wred[tid >> 6][k][0] = g0;
      wred[tid >> 6][k][1] = g1;
    }
  }
  __syncthreads();
  if (tid < 64) {
    const int l = tid & 31, j = tid >> 5;
    float acc = 0.f;
#pragma unroll
    for (int k = 0; k < 4; ++k) {
      const float gk =
          wred[0][k][j] + wred[1][k][j] + wred[2][k][j] + wred[3][k][j];
      acc += W2[(128 + rvt * 4 + k) * LL + l] * gk;
    }
    atomicAdd(&out[gb * (LL * 2) + l * 2 + j], acc);
  }
}

extern "C" void kernel_launch(void* const* d_in, const int* in_sizes, int n_in,
                              void* d_out, int out_size, void* d_ws,
                              size_t ws_size, hipStream_t stream) {
  const float* user = (const float*)d_in[0];
  const float* item = (const float*)d_in[1];
  const float* att = (const float*)d_in[2];
  const float* adj = (const float*)d_in[3];
  const float* iw = (const float*)d_in[4];
  const float* W1 = (const float*)d_in[5];
  const float* W2 = (const float*)d_in[6];
  float* out = (float*)d_out;
  float* c = (float*)d_ws;  // 2*16*2048 floats

  stc_kernel<<<dim3(16, BB), 256, 0, stream>>>(user, item, att, adj, iw, W1,
                                               W2, c, out);
  gather_kernel<<<dim3(16, BB), 256, 0, stream>>>(user, item, att, W1, c, W2,
                                                  out);
}

// Round 3
// 108.093 us; speedup vs baseline: 1.4129x; 1.0533x over previous
//
#include <hip/hip_runtime.h>
#include <math.h>

// Problem constants
#define BB 16      // batch
#define LL 32      // L
#define AA 2046    // attributor cols
#define MM 2048    // M = A + 2
#define NROWS 192  // 6L
#define CT 32      // column tiles
#define CPB 64     // columns per block (c-space)

// c-space mapping: c in [0,2045] -> n = c+1 (att col c); c=2046 -> n=0 (user
// column, no W1); c=2047 -> n=M-1 (item column, no W1). This keeps att float2
// loads 8B-aligned and makes the value phase use the same layout as s/t.

// ---------------------------------------------------------------------------
// Single fused kernel (plus a 4KB memset). grid (32 ctiles, 16 b) x 256 thr.
// Per block (owns 64 c-space columns, everything stays in LDS):
//   prep    : redundant K/Q projections -> u_j[64], v_j[64] weights
//   st      : thread (cq=tid&15, rg=tid>>4) = col-quad x 8-row group over
//             rows 0..127 -> partial s/t dots in stS
//   cweight : 128 threads combine -> cs[j][64] = sigmoid(d_j)*adj  (LDS only)
//   value   : thread (cq, rg) = col-quad x 4-row group over rows 128..191,
//             g_j[r] partials; shuffle-reduce over the 16 col-quads
//   project : 64 threads: partial out[b,l,j] = sum_r W2[128+r,l]*g_j[r],
//             one atomicAdd per (block,l,j)
// No inter-block dependencies -> single dispatch, deep TLP (2 blocks/CU).
// ---------------------------------------------------------------------------
__global__ __launch_bounds__(256) void fused_kernel(
    const float* __restrict__ user, const float* __restrict__ item,
    const float* __restrict__ att, const float* __restrict__ adj,
    const float* __restrict__ iw, const float* __restrict__ W1,
    const float* __restrict__ W2, float* __restrict__ out) {
  const int ctile = blockIdx.x, b = blockIdx.y, tid = threadIdx.x;
  __shared__ float KQ[4][LL];
  __shared__ float uvs[4][64];
  __shared__ float stS[16][16][4][2];  // [rowgroup][colquad][colInQuad][j]
  __shared__ float cs[2][CPB];
  __shared__ float gred[16][4][2];     // [rowgroup][rowInGroup][j]

  // ---- prep stage 1: K/Q boundary projections ----
  if (tid < 128) {
    const int q = tid >> 5, l = tid & 31;
    const float* __restrict__ src = (q == 0 || q == 2) ? user : item;
    const int rbase = (q < 2) ? 64 : 0;  // K rows 64..127, Q rows 0..63
    float acc = 0.f;
#pragma unroll
    for (int r = 0; r < 64; ++r)
      acc += fmaxf(src[b * NROWS + rbase + r], 0.f) * W2[(rbase + r) * LL + l];
    KQ[q][l] = acc;  // 0:K0(user) 1:K1(item) 2:Q0(user) 3:Q1(item)
  }
  __syncthreads();
  {  // ---- prep stage 2: u/v weights ----
    const int which = tid >> 6, r = tid & 63;
    const int wrow = (which < 2) ? r : 64 + r;
    float acc = 0.f;
#pragma unroll
    for (int l = 0; l < LL; ++l) acc += W2[wrow * LL + l] * KQ[which][l];
    uvs[which][r] = acc;  // 0:u0 1:u1 2:v0 3:v1
  }
  __syncthreads();

  // ---- s/t partials: col-quad x 8-row group ----
  {
    const int cq = tid & 15, rg = tid >> 4;
    const int c0 = ctile * CPB + cq * 4;
    const float* __restrict__ wj0 = uvs[(rg < 8) ? 0 : 2];
    const float* __restrict__ wj1 = uvs[(rg < 8) ? 1 : 3];
    const int rbase = (rg < 8) ? 0 : 64;
    const int rrow0 = (rg & 7) * 8 + rbase;
    float a[4][2] = {};
#pragma unroll
    for (int i = 0; i < 8; ++i) {
      const int r = rrow0 + i;
      const int widx = r - rbase;
      const size_t arow = (size_t)(b * NROWS + r) * AA;
      const size_t wrow = (size_t)r * AA;
      const float2 av0 = *(const float2*)(att + arow + c0);
      const float2 wv0 = *(const float2*)(W1 + wrow + c0);
      const float v0 = fmaxf(av0.x * wv0.x, 0.f);
      const float v1 = fmaxf(av0.y * wv0.y, 0.f);
      float v2, v3;
      if (c0 + 2 < AA) {
        const float2 av1 = *(const float2*)(att + arow + c0 + 2);
        const float2 wv1 = *(const float2*)(W1 + wrow + c0 + 2);
        v2 = fmaxf(av1.x * wv1.x, 0.f);
        v3 = fmaxf(av1.y * wv1.y, 0.f);
      } else {  // tail quad: c 2046 -> user, 2047 -> item (no W1)
        v2 = fmaxf(user[b * NROWS + r], 0.f);
        v3 = fmaxf(item[b * NROWS + r], 0.f);
      }
      const float u0 = wj0[widx], u1 = wj1[widx];
      a[0][0] += v0 * u0; a[0][1] += v0 * u1;
      a[1][0] += v1 * u0; a[1][1] += v1 * u1;
      a[2][0] += v2 * u0; a[2][1] += v2 * u1;
      a[3][0] += v3 * u0; a[3][1] += v3 * u1;
    }
#pragma unroll
    for (int k = 0; k < 4; ++k) {
      stS[rg][cq][k][0] = a[k][0];
      stS[rg][cq][k][1] = a[k][1];
    }
  }
  __syncthreads();

  // ---- cweight: 64 cols x 2 targets ----
  if (tid < 128) {
    const int col = tid >> 1, j = tid & 1;
    const int cq = col >> 2, ci = col & 3;
    float s = 0.f, t = 0.f;
#pragma unroll
    for (int rg = 0; rg < 8; ++rg) s += stS[rg][cq][ci][j];
#pragma unroll
    for (int rg = 8; rg < 16; ++rg) t += stS[rg][cq][ci][j];
    const int cc = ctile * CPB + col;
    const int n = (cc < AA) ? cc + 1 : ((cc == AA) ? 0 : MM - 1);
    const size_t tcol = j ? (MM - 1) : 0;
    const float an = adj[(size_t)n * MM + tcol];
    const float wn = an * iw[(size_t)n * MM + tcol];
    const float wt = adj[tcol * MM + n] * iw[tcol * MM + n];
    const float d = s * wn - t * wt;
    const float e = expf(-fabsf(d));
    const float sig = (d > 0.f) ? 1.f / (1.f + e) : e / (1.f + e);
    cs[j][col] = sig * an;
  }
  __syncthreads();

  // ---- value gather: col-quad x 4-row group over rows 128..191 ----
  {
    const int cq = tid & 15, rg = tid >> 4;
    const int c0 = ctile * CPB + cq * 4;
    const float c00 = cs[0][cq * 4], c01 = cs[0][cq * 4 + 1];
    const float c02 = cs[0][cq * 4 + 2], c03 = cs[0][cq * 4 + 3];
    const float c10 = cs[1][cq * 4], c11 = cs[1][cq * 4 + 1];
    const float c12 = cs[1][cq * 4 + 2], c13 = cs[1][cq * 4 + 3];
    float g[4][2] = {};
#pragma unroll
    for (int i = 0; i < 4; ++i) {
      const int r = 128 + rg * 4 + i;
      const size_t arow = (size_t)(b * NROWS + r) * AA;
      const size_t wrow = (size_t)r * AA;
      const float2 av0 = *(const float2*)(att + arow + c0);
      const float2 wv0 = *(const float2*)(W1 + wrow + c0);
      const float v0 = fmaxf(av0.x * wv0.x, 0.f);
      const float v1 = fmaxf(av0.y * wv0.y, 0.f);
      float v2, v3;
      if (c0 + 2 < AA) {
        const float2 av1 = *(const float2*)(att + arow + c0 + 2);
        const float2 wv1 = *(const float2*)(W1 + wrow + c0 + 2);
        v2 = fmaxf(av1.x * wv1.x, 0.f);
        v3 = fmaxf(av1.y * wv1.y, 0.f);
      } else {
        v2 = fmaxf(user[b * NROWS + r], 0.f);
        v3 = fmaxf(item[b * NROWS + r], 0.f);
      }
      g[i][0] += v0 * c00 + v1 * c01 + v2 * c02 + v3 * c03;
      g[i][1] += v0 * c10 + v1 * c11 + v2 * c12 + v3 * c13;
    }
    // reduce over the 16 col-quads (lanes xor 1,2,4,8 within 16-lane groups)
#pragma unroll
    for (int m = 8; m >= 1; m >>= 1) {
#pragma unroll
      for (int i = 0; i < 4; ++i) {
        g[i][0] += __shfl_xor(g[i][0], m, 16);
        g[i][1] += __shfl_xor(g[i][1], m, 16);
      }
    }
    if (cq == 0) {
#pragma unroll
      for (int i = 0; i < 4; ++i) {
        gred[rg][i][0] = g[i][0];
        gred[rg][i][1] = g[i][1];
      }
    }
  }
  __syncthreads();

  // ---- project partial g through W2, atomic-accumulate ----
  if (tid < 64) {
    const int l = tid & 31, j = tid >> 5;
    float acc = 0.f;
#pragma unroll
    for (int rv = 0; rv < 64; ++rv)
      acc += W2[(128 + rv) * LL + l] * gred[rv >> 2][rv & 3][j];
    atomicAdd(&out[b * (LL * 2) + l * 2 + j], acc);
  }
}

extern "C" void kernel_launch(void* const* d_in, const int* in_sizes, int n_in,
                              void* d_out, int out_size, void* d_ws,
                              size_t ws_size, hipStream_t stream) {
  const float* user = (const float*)d_in[0];
  const float* item = (const float*)d_in[1];
  const float* att = (const float*)d_in[2];
  const float* adj = (const float*)d_in[3];
  const float* iw = (const float*)d_in[4];
  const float* W1 = (const float*)d_in[5];
  const float* W2 = (const float*)d_in[6];
  float* out = (float*)d_out;

  hipMemsetAsync(d_out, 0, sizeof(float) * (size_t)out_size, stream);
  fused_kernel<<<dim3(CT, BB), 256, 0, stream>>>(user, item, att, adj, iw, W1,
                                                 W2, out);
}